// Round 11
// baseline (47673.334 us; speedup 1.0000x reference)
//
#include <hip/hip_runtime.h>

#define SEQLEN 8192
#define EMB    1024
#define HID    2048
#define NCHARS 256
#define DIN    3072   // EMB + HID
#define R4     8192   // 4*HID

typedef __bf16 bf16x8 __attribute__((ext_vector_type(8)));
typedef float  f32x4  __attribute__((ext_vector_type(4)));
typedef unsigned u32x4 __attribute__((ext_vector_type(4)));

__device__ __forceinline__ unsigned short f2bf(float f) {
    unsigned int u = __float_as_uint(f);
    u = (u + 0x7fffu + ((u >> 16) & 1u)) >> 16;   // RNE
    return (unsigned short)u;
}

__device__ __forceinline__ float bf2f(unsigned short u) {
    return __uint_as_float((unsigned)u << 16);
}

__device__ __forceinline__ float sigmoid_fast(float x) {
    return 1.0f / (1.0f + __expf(-x));
}

__device__ __forceinline__ float tanh_fast(float x) {
    float a = fabsf(x);
    float e = __expf(-2.0f * a);
    float r = (1.0f - e) / (1.0f + e);
    return copysignf(r, x);
}

// LLC-coherent 16B load (bypass L1+local L2; per-dword atomicity of an aligned
// dwordx4 is guaranteed — each dword comes whole from one cache-line read).
__device__ __forceinline__ u32x4 llc_load4(const unsigned* p) {
    u32x4 r;
    asm volatile("global_load_dwordx4 %0, %1, off sc0 sc1\n\ts_waitcnt vmcnt(0)"
                 : "=v"(r) : "v"(p) : "memory");
    return r;
}

// LLC write-through publish store.
__device__ __forceinline__ void llc_store(unsigned* p, unsigned v) {
    asm volatile("global_store_dword %0, %1, off sc0 sc1" :: "v"(p), "v"(v) : "memory");
}

#define PIN_WEIGHTS(wv) asm volatile("" :                               \
        "+v"(wv[0]), "+v"(wv[1]), "+v"(wv[2]), "+v"(wv[3]),             \
        "+v"(wv[4]), "+v"(wv[5]), "+v"(wv[6]), "+v"(wv[7]),             \
        "+v"(wv[8]), "+v"(wv[9]), "+v"(wv[10]), "+v"(wv[11]),           \
        "+v"(wv[12]), "+v"(wv[13]), "+v"(wv[14]), "+v"(wv[15]),         \
        "+v"(wv[16]), "+v"(wv[17]), "+v"(wv[18]), "+v"(wv[19]),         \
        "+v"(wv[20]), "+v"(wv[21]), "+v"(wv[22]), "+v"(wv[23]),         \
        "+v"(wv[24]), "+v"(wv[25]), "+v"(wv[26]), "+v"(wv[27]),         \
        "+v"(wv[28]), "+v"(wv[29]), "+v"(wv[30]), "+v"(wv[31]))

// ---------------- prep: gather emb rows -> bf16 A, W4 input-cols -> bf16 B ----------------
__global__ __launch_bounds__(256) void prep_a(const int* __restrict__ seq,
                                              const float* __restrict__ emb,
                                              unsigned short* __restrict__ A) {
    const int t = blockIdx.x, k4 = threadIdx.x;          // 256 float4 per row == EMB
    const float4 v = ((const float4*)(emb + (size_t)seq[t] * EMB))[k4];
    ushort4 o;
    o.x = f2bf(v.x); o.y = f2bf(v.y); o.z = f2bf(v.z); o.w = f2bf(v.w);
    ((ushort4*)(A + (size_t)t * EMB))[k4] = o;
}

__global__ __launch_bounds__(256) void prep_b(const float* __restrict__ Wf,
                                              const float* __restrict__ Wi,
                                              const float* __restrict__ Wo,
                                              const float* __restrict__ Wc,
                                              unsigned short* __restrict__ B) {
    const int r = blockIdx.x, k4 = threadIdx.x;          // r = g*2048 + j
    const int g = r >> 11, j = r & 2047;
    const float* W = (g == 0) ? Wf : (g == 1) ? Wi : (g == 2) ? Wo : Wc;
    const float4 v = ((const float4*)(W + (size_t)j * DIN))[k4];   // cols [0,1024)
    ushort4 o;
    o.x = f2bf(v.x); o.y = f2bf(v.y); o.z = f2bf(v.z); o.w = f2bf(v.w);
    ((ushort4*)(B + (size_t)r * EMB))[k4] = o;
}

// ---------------- Zx = A(bf16) @ B(bf16)^T  -> bf16 [8192][8192] ----------------
__global__ __launch_bounds__(256) void gemm_zx(const unsigned short* __restrict__ A,
                                               const unsigned short* __restrict__ B,
                                               unsigned short* __restrict__ C) {
    constexpr int K = EMB;
    __shared__ __align__(16) unsigned short As[128 * 32];
    __shared__ __align__(16) unsigned short Bs[128 * 32];
    const int m0 = blockIdx.y * 128, n0 = blockIdx.x * 128;
    const int tid = threadIdx.x, lane = tid & 63;
    const int w = tid >> 6, wr = w >> 1, wc = w & 1;
    f32x4 acc[4][4] = {};
    for (int k0 = 0; k0 < K; k0 += 32) {
        __syncthreads();
        #pragma unroll
        for (int s = 0; s < 2; ++s) {
            const int e = (tid + s * 256) * 8;           // linear bf16 elem in 128x32 tile
            const int row = e >> 5, kk = e & 31;
            *(uint4*)&As[e] = *(const uint4*)&A[(size_t)(m0 + row) * K + k0 + kk];
            *(uint4*)&Bs[e] = *(const uint4*)&B[(size_t)(n0 + row) * K + k0 + kk];
        }
        __syncthreads();
        bf16x8 af[4], bg[4];
        #pragma unroll
        for (int mi = 0; mi < 4; ++mi)
            af[mi] = *(const bf16x8*)&As[(wr * 64 + mi * 16 + (lane & 15)) * 32 + (lane >> 4) * 8];
        #pragma unroll
        for (int ni = 0; ni < 4; ++ni)
            bg[ni] = *(const bf16x8*)&Bs[(wc * 64 + ni * 16 + (lane & 15)) * 32 + (lane >> 4) * 8];
        #pragma unroll
        for (int mi = 0; mi < 4; ++mi)
            #pragma unroll
            for (int ni = 0; ni < 4; ++ni)
                acc[mi][ni] = __builtin_amdgcn_mfma_f32_16x16x32_bf16(af[mi], bg[ni], acc[mi][ni], 0, 0, 0);
    }
    #pragma unroll
    for (int mi = 0; mi < 4; ++mi)
        #pragma unroll
        for (int ni = 0; ni < 4; ++ni)
            #pragma unroll
            for (int r = 0; r < 4; ++r)
                C[(size_t)(m0 + wr * 64 + mi * 16 + (lane >> 4) * 4 + r) * R4
                  + (n0 + wc * 64 + ni * 16 + (lane & 15))] = f2bf(acc[mi][ni][r]);
}

// ---------------- persistent sequential LSTM ----------------
// 256 blocks x 512 threads. Block b owns units j = b*8 + w (wave w = tid>>6).
// Sync words: 32-bit SELF-TAGGED (h_bits&~0xF)|((t+1)&0xF) in slot (t+1)&1.
// r9 RESULT: weight residency is NOT the bottleneck (pin inert, time flat) —
// critical path is the sync chain. This round shortens that chain:
//  (1) Zx prefetch issued AFTER bar#1 (was: right before the poll, whose
//      vmcnt(0) drained the ~900cy HBM loads on the critical path).
//  (2) bar#2 DELETED via double-buffered LDS h_lds[2][HID]. WAR-safe by
//      transitivity: observing tag t+2 => producers finished step t+1 =>
//      their bar#1 coupled all 8 of their waves having observed tag t+1 on
//      ALL 2048 units => every block (incl. this one) published t+1 => every
//      wave finished its step-t matvec reads of h_lds[t&1]. So staging t+2
//      into h_lds[t&1] races nothing (same-block and cross-block).
//  (3) Publish IMMEDIATELY after gates (no barrier in front) — flags become
//      globally visible one barrier-latency earlier each step.
__global__ __launch_bounds__(512, 2) void lstm_seq(
    const float* __restrict__ Wf, const float* __restrict__ Wi,
    const float* __restrict__ Wo, const float* __restrict__ Wc,
    const float* __restrict__ bfv, const float* __restrict__ biv,
    const float* __restrict__ bov, const float* __restrict__ bcv,
    const unsigned short* __restrict__ Zx, float* __restrict__ Hmat,
    unsigned* __restrict__ sync,
    float* __restrict__ outH, float* __restrict__ outC)
{
    __shared__ __align__(16) float h_lds[2][HID];        // 16 KB, parity-indexed
    const int tid = threadIdx.x;
    const int lane = tid & 63;
    const int w = tid >> 6;                              // 0..7
    const int b = blockIdx.x;                            // 0..255
    const int j = b * 8 + w;                             // hidden unit

    // --- load h-part weights into registers ---
    f32x4 wv[32];                                        // [g*8+q]
    {
        const float* Wp[4] = {Wf, Wi, Wo, Wc};
        #pragma unroll
        for (int g = 0; g < 4; ++g) {
            const float* src = Wp[g] + (size_t)j * DIN + EMB;
            #pragma unroll
            for (int q = 0; q < 8; ++q)
                wv[g * 8 + q] = *(const f32x4*)(src + q * 256 + lane * 4);
        }
    }
    PIN_WEIGHTS(wv);

    const float bias0 = bfv[j], bias1 = biv[j], bias2 = bov[j], bias3 = bcv[j];

    float zx0 = bf2f(Zx[(size_t)0 * R4 + 0 * HID + j]);
    float zx1 = bf2f(Zx[(size_t)0 * R4 + 1 * HID + j]);
    float zx2 = bf2f(Zx[(size_t)0 * R4 + 2 * HID + j]);
    float zx3 = bf2f(Zx[(size_t)0 * R4 + 3 * HID + j]);

    float cst = 0.0f, hlast = 0.0f;
    const int segbase = w * 256 + lane * 4;              // this lane's 4 unit slots

    for (int t = 0; t < SEQLEN; ++t) {
        PIN_WEIGHTS(wv);                                 // (inert per r9; kept for A/B purity)

        // --- poll + stage h_{t-1} segment (256 floats per wave) into LDS[t&1] ---
        if (t == 0) {
            *(f32x4*)&h_lds[0][segbase] = (f32x4){0.f, 0.f, 0.f, 0.f};
        } else {
            const unsigned tag = (unsigned)(t & 15);
            const unsigned* S = sync + (size_t)(t & 1) * HID + segbase;
            u32x4 v;
            for (;;) {
                v = llc_load4(S);
                const bool ok = ((v[0] & 15u) == tag) & ((v[1] & 15u) == tag) &
                                ((v[2] & 15u) == tag) & ((v[3] & 15u) == tag);
                if (__all((int)ok)) break;
            }
            f32x4 hv;
            hv[0] = __uint_as_float(v[0]); hv[1] = __uint_as_float(v[1]);
            hv[2] = __uint_as_float(v[2]); hv[3] = __uint_as_float(v[3]);
            *(f32x4*)&h_lds[t & 1][segbase] = hv;
        }
        __syncthreads();                                  // bar#1: staging -> matvec

        // --- issue next step's Zx loads now (latency overlaps matvec..next poll) ---
        float nzx0 = 0.f, nzx1 = 0.f, nzx2 = 0.f, nzx3 = 0.f;
        if (t + 1 < SEQLEN) {
            const size_t base = (size_t)(t + 1) * R4 + j;
            nzx0 = bf2f(Zx[base]);           nzx1 = bf2f(Zx[base + HID]);
            nzx2 = bf2f(Zx[base + 2 * HID]); nzx3 = bf2f(Zx[base + 3 * HID]);
        }

        // --- matvec: 128 FMAs/lane, 4 independent accumulator chains ---
        float a0 = 0.f, a1 = 0.f, a2 = 0.f, a3 = 0.f;
        #pragma unroll
        for (int q = 0; q < 8; ++q) {
            const f32x4 hv = *(const f32x4*)&h_lds[t & 1][q * 256 + lane * 4];
            #pragma unroll
            for (int u = 0; u < 4; ++u) {
                a0 = fmaf(wv[0 * 8 + q][u], hv[u], a0);
                a1 = fmaf(wv[1 * 8 + q][u], hv[u], a1);
                a2 = fmaf(wv[2 * 8 + q][u], hv[u], a2);
                a3 = fmaf(wv[3 * 8 + q][u], hv[u], a3);
            }
        }

        // --- reduce across the 64 lanes ---
        #pragma unroll
        for (int off = 32; off; off >>= 1) {
            a0 += __shfl_xor(a0, off, 64);
            a1 += __shfl_xor(a1, off, 64);
            a2 += __shfl_xor(a2, off, 64);
            a3 += __shfl_xor(a3, off, 64);
        }

        // --- gates (all lanes redundantly; lane0 publishes IMMEDIATELY) ---
        const float zf = zx0 + bias0 + a0;
        const float zi = zx1 + bias1 + a1;
        const float zo = zx2 + bias2 + a2;
        const float zc = zx3 + bias3 + a3;
        const float fg = sigmoid_fast(zf);
        const float ig = sigmoid_fast(zi);
        const float og = sigmoid_fast(zo);
        const float ct = tanh_fast(zc);
        cst = fg * cst + ig * ct;
        const float hn = og * tanh_fast(cst);
        hlast = hn;

        if (lane == 0) {
            const unsigned pw = (__float_as_uint(hn) & ~15u) | ((unsigned)(t + 1) & 15u);
            llc_store(&sync[(size_t)((t + 1) & 1) * HID + j], pw);
            Hmat[(size_t)t * HID + j] = hn;               // acks drain in next poll
        }
        // (no bar#2 — LDS double buffer + flag transitivity make it redundant)

        zx0 = nzx0; zx1 = nzx1; zx2 = nzx2; zx3 = nzx3;
    }

    if (lane == 0) { outH[j] = hlast; outC[j] = cst; }
}

// ---------------- out = Hmat @ Wout^T + bout ----------------
__global__ __launch_bounds__(256) void out_gemm(const float* __restrict__ H,
                                                const float* __restrict__ Wout,
                                                const float* __restrict__ bout,
                                                float* __restrict__ out) {
    __shared__ float Hs[4][HID];                         // 32 KB
    const int t0 = blockIdx.x * 4;
    const int tid = threadIdx.x;
    {
        const float4* src = (const float4*)(H + (size_t)t0 * HID);
        float4* dst = (float4*)Hs;
        #pragma unroll
        for (int i = tid; i < 4 * HID / 4; i += 256) dst[i] = src[i];
    }
    __syncthreads();
    const int w = tid >> 6, lane = tid & 63;
    for (int ch = w; ch < NCHARS; ch += 4) {
        const float* wrow = Wout + (size_t)ch * HID;
        float acc0 = 0.f, acc1 = 0.f, acc2 = 0.f, acc3 = 0.f;
        #pragma unroll
        for (int q = 0; q < 8; ++q) {
            const int k = q * 256 + lane * 4;
            const float4 wvv = *(const float4*)(wrow + k);
            const float4 h0 = *(const float4*)&Hs[0][k];
            const float4 h1 = *(const float4*)&Hs[1][k];
            const float4 h2 = *(const float4*)&Hs[2][k];
            const float4 h3 = *(const float4*)&Hs[3][k];
            acc0 = fmaf(wvv.x, h0.x, acc0); acc0 = fmaf(wvv.y, h0.y, acc0);
            acc0 = fmaf(wvv.z, h0.z, acc0); acc0 = fmaf(wvv.w, h0.w, acc0);
            acc1 = fmaf(wvv.x, h1.x, acc1); acc1 = fmaf(wvv.y, h1.y, acc1);
            acc1 = fmaf(wvv.z, h1.z, acc1); acc1 = fmaf(wvv.w, h1.w, acc1);
            acc2 = fmaf(wvv.x, h2.x, acc2); acc2 = fmaf(wvv.y, h2.y, acc2);
            acc2 = fmaf(wvv.z, h2.z, acc2); acc2 = fmaf(wvv.w, h2.w, acc2);
            acc3 = fmaf(wvv.x, h3.x, acc3); acc3 = fmaf(wvv.y, h3.y, acc3);
            acc3 = fmaf(wvv.w, h3.w, acc3); acc3 = fmaf(wvv.z, h3.z, acc3);
        }
        #pragma unroll
        for (int off = 32; off; off >>= 1) {
            acc0 += __shfl_xor(acc0, off, 64);
            acc1 += __shfl_xor(acc1, off, 64);
            acc2 += __shfl_xor(acc2, off, 64);
            acc3 += __shfl_xor(acc3, off, 64);
        }
        if (lane == 0) {
            const float bb = bout[ch];
            out[(size_t)(t0 + 0) * NCHARS + ch] = acc0 + bb;
            out[(size_t)(t0 + 1) * NCHARS + ch] = acc1 + bb;
            out[(size_t)(t0 + 2) * NCHARS + ch] = acc2 + bb;
            out[(size_t)(t0 + 3) * NCHARS + ch] = acc3 + bb;
        }
    }
}

extern "C" void kernel_launch(void* const* d_in, const int* in_sizes, int n_in,
                              void* d_out, int out_size, void* d_ws, size_t ws_size,
                              hipStream_t stream) {
    (void)in_sizes; (void)n_in; (void)out_size; (void)ws_size;
    const int*   seq  = (const int*)  d_in[0];
    const float* emb  = (const float*)d_in[1];
    const float* Wf   = (const float*)d_in[2];
    const float* bfv  = (const float*)d_in[3];
    const float* Wi   = (const float*)d_in[4];
    const float* biv  = (const float*)d_in[5];
    const float* Wo   = (const float*)d_in[6];
    const float* bov  = (const float*)d_in[7];
    const float* Wc   = (const float*)d_in[8];
    const float* bcv  = (const float*)d_in[9];
    const float* Wout = (const float*)d_in[10];
    const float* bout = (const float*)d_in[11];
    float* out = (float*)d_out;

    char* ws = (char*)d_ws;
    size_t off = 0;
    unsigned short* Zx = (unsigned short*)(ws + off);  off += (size_t)SEQLEN * R4 * 2;    // 128 MB
    float* Hm = (float*)(ws + off);                    off += (size_t)SEQLEN * HID * 4;   // 64 MB
    unsigned short* Abf = (unsigned short*)(ws + off); off += (size_t)SEQLEN * EMB * 2;   // 16 MB
    unsigned short* Bbf = (unsigned short*)(ws + off); off += (size_t)R4 * EMB * 2;       // 16 MB
    unsigned* sync = (unsigned*)(ws + off);            off += (size_t)2 * HID * 4;        // 16 KB
    // no memset needed: tag nibble of 0xAA poison (0xA) never matches first tags {1,2}

    prep_a<<<SEQLEN, 256, 0, stream>>>(seq, emb, Abf);
    prep_b<<<R4, 256, 0, stream>>>(Wf, Wi, Wo, Wc, Bbf);

    dim3 gg(R4 / 128, SEQLEN / 128);
    gemm_zx<<<gg, 256, 0, stream>>>(Abf, Bbf, Zx);

    lstm_seq<<<256, 512, 0, stream>>>(Wf, Wi, Wo, Wc, bfv, biv, bov, bcv,
                                      Zx, Hm, sync,
                                      out + (size_t)SEQLEN * NCHARS,
                                      out + (size_t)SEQLEN * NCHARS + HID);

    out_gemm<<<SEQLEN / 4, 256, 0, stream>>>(Hm, Wout, bout, out);
}